// Round 1
// baseline (176.471 us; speedup 1.0000x reference)
//
#include <hip/hip_runtime.h>
#include <cmath>

// Problem geometry (fixed by the reference: im is (1, 4096, 4096, 3) f32 NHWC)
constexpr int H   = 4096;
constexpr int W   = 4096;
constexpr int C   = 3;
constexpr int WF  = W * C;      // 12288 floats per image row
constexpr int RPT = 16;         // output rows per thread

// Fused: Anscombe 2*sqrt(x+0.375) -> separable 3x3 Gaussian (zero pad) ->
// clip [0,255] -> inverse-Anscombe polynomial.
// Each thread owns one flat-float column f (channel-preserving: horizontal
// pixel neighbors are at f-3 / f+3) and walks RPT rows with a rolling
// 3-register vertical window of horizontal 3-tap sums.
__global__ __launch_bounds__(256) void anscombe_gauss_kernel(
    const float* __restrict__ in, float* __restrict__ out,
    float wa, float wb, float c1, float c3)
{
    const int f  = blockIdx.x * 256 + threadIdx.x;   // 0 .. WF-1
    const int h0 = blockIdx.y * RPT;
    const bool hasL = (f >= 3);
    const bool hasR = (f + 3 < WF);

    auto hsum = [&](int h) -> float {
        if ((unsigned)h >= (unsigned)H) return 0.0f;   // zero pad in AT domain
        const float* row = in + (long)h * WF;
        float atc = 2.0f * sqrtf(row[f] + 0.375f);
        float atm = hasL ? 2.0f * sqrtf(row[f - 3] + 0.375f) : 0.0f;
        float atp = hasR ? 2.0f * sqrtf(row[f + 3] + 0.375f) : 0.0f;
        return wa * (atm + atp) + wb * atc;
    };

    float hp = hsum(h0 - 1);
    float hc = hsum(h0);

    #pragma unroll
    for (int r = 0; r < RPT; ++r) {
        const int h = h0 + r;
        float hn = hsum(h + 1);
        float y  = wa * (hp + hn) + wb * hc;
        y = fminf(fmaxf(y, 0.0f), 255.0f);
        // y >= ~0.6 everywhere (input >= 0, center tap always present), no div-by-0
        float ry  = 1.0f / y;
        float ry2 = ry * ry;
        float v = 0.25f * y * y + c1 * ry - 1.375f * ry2 + c3 * ry2 * ry - 0.125f;
        out[(long)h * WF + f] = v;
        hp = hc; hc = hn;
    }
}

extern "C" void kernel_launch(void* const* d_in, const int* in_sizes, int n_in,
                              void* d_out, int out_size, void* d_ws, size_t ws_size,
                              hipStream_t stream) {
    const float* in = (const float*)d_in[0];
    float* out      = (float*)d_out;

    // Separable Gaussian weights, computed in double on host.
    // 2D normalized kernel == outer([a,b,a],[a,b,a]) with a+b+a == 1.
    const double sig2x2 = 2.0 * 1.3 * 1.3;
    const double e1     = std::exp(-1.0 / sig2x2);
    const double inv1d  = 1.0 / (1.0 + 2.0 * e1);
    const float  wa     = (float)(e1 * inv1d);
    const float  wb     = (float)inv1d;

    const double s  = std::sqrt(1.5);
    const float  c1 = (float)(0.25  * s);
    const float  c3 = (float)(0.625 * s);

    dim3 grid(WF / 256, H / RPT);
    anscombe_gauss_kernel<<<grid, 256, 0, stream>>>(in, out, wa, wb, c1, c3);
}

// Round 2
// 95.342 us; speedup vs baseline: 1.8509x; 1.8509x over previous
//
#include <hip/hip_runtime.h>
#include <cmath>

// Problem geometry (fixed: im is (1, 4096, 4096, 3) f32 NHWC)
constexpr int H   = 4096;
constexpr int W   = 4096;
constexpr int C   = 3;
constexpr int WF  = W * C;     // 12288 floats per image row
constexpr int TW  = 1024;      // tile width in floats = 256 threads * 4
constexpr int RPT = 16;        // output rows per block

// Fused Anscombe -> separable 3x3 Gaussian (zero pad) -> clip -> inverse
// Anscombe. Per stage (one image row): every thread loads a float4, computes
// the Anscombe transform ONCE per element (4 sqrt), stages it in an LDS line
// buffer (double-buffered, 1 barrier/stage); horizontal 3-tap comes from LDS,
// vertical 3-tap from a rolling register window of horizontal sums.
__global__ __launch_bounds__(256) void anscombe_gauss_kernel(
    const float* __restrict__ in, float* __restrict__ out,
    float wa, float wb, float c1, float c3)
{
    __shared__ __align__(16) float lds[2][TW + 8];

    const int tid      = threadIdx.x;
    const int bx       = blockIdx.x;
    const int tilebase = bx * TW;
    const int gc       = tilebase + tid * 4;     // global flat column of elem 0
    const int h0       = blockIdx.y * RPT;

    // Threads 0/1 additionally stage the left/right 4-float halo.
    const int  halo_lds = (tid == 0) ? 0 : (TW + 4);
    const int  halo_gc  = (tid == 0) ? (tilebase - 4) : (tilebase + TW);
    const bool halo_ok  = (tid == 0) ? (bx > 0) : (bx + 1 < (int)gridDim.x);

    float4 hp = make_float4(0.f, 0.f, 0.f, 0.f);
    float4 hc = hp;

    #pragma unroll 2
    for (int s = 0; s < RPT + 2; ++s) {
        const int  h     = h0 - 1 + s;
        const bool rowok = (unsigned)h < (unsigned)H;
        float* Lb = lds[s & 1];

        // ---- load + Anscombe (OOB rows: v = -0.375 so at = 2*sqrt(0) = 0)
        float4 v = make_float4(-0.375f, -0.375f, -0.375f, -0.375f);
        if (rowok) v = *(const float4*)(in + (long)h * WF + gc);
        float4 a;
        a.x = 2.0f * __builtin_amdgcn_sqrtf(v.x + 0.375f);
        a.y = 2.0f * __builtin_amdgcn_sqrtf(v.y + 0.375f);
        a.z = 2.0f * __builtin_amdgcn_sqrtf(v.z + 0.375f);
        a.w = 2.0f * __builtin_amdgcn_sqrtf(v.w + 0.375f);
        *(float4*)(Lb + 4 + tid * 4) = a;

        if (tid < 2) {
            float4 w4 = make_float4(-0.375f, -0.375f, -0.375f, -0.375f);
            if (rowok && halo_ok)
                w4 = *(const float4*)(in + (long)h * WF + halo_gc);
            float4 aw;
            aw.x = 2.0f * __builtin_amdgcn_sqrtf(w4.x + 0.375f);
            aw.y = 2.0f * __builtin_amdgcn_sqrtf(w4.y + 0.375f);
            aw.z = 2.0f * __builtin_amdgcn_sqrtf(w4.z + 0.375f);
            aw.w = 2.0f * __builtin_amdgcn_sqrtf(w4.w + 0.375f);
            *(float4*)(Lb + halo_lds) = aw;
        }
        __syncthreads();

        // ---- horizontal 3-tap from LDS (12 floats cover taps for 4 outputs)
        const float4* Lp = (const float4*)(Lb + tid * 4);
        float4 q0 = Lp[0], q1 = Lp[1], q2 = Lp[2];
        float4 hn;
        hn.x = wa * (q0.y + q1.w) + wb * q1.x;
        hn.y = wa * (q0.z + q2.x) + wb * q1.y;
        hn.z = wa * (q0.w + q2.y) + wb * q1.z;
        hn.w = wa * (q1.x + q2.z) + wb * q1.w;

        // ---- vertical 3-tap + clip + inverse-Anscombe, store
        if (s >= 2) {
            const int ho = h0 + s - 2;
            float4 o;
            #pragma unroll
            for (int j = 0; j < 4; ++j) {
                float y = wa * (((const float*)&hp)[j] + ((const float*)&hn)[j])
                        + wb * ((const float*)&hc)[j];
                y = fminf(fmaxf(y, 0.0f), 255.0f);
                // y >= ~0.19 always (center tap always present), rcp is safe
                float ry = __builtin_amdgcn_rcpf(y);
                ((float*)&o)[j] =
                    fmaf(0.25f * y, y,
                         fmaf(ry, fmaf(ry, fmaf(ry, c3, -1.375f), c1), -0.125f));
            }
            *(float4*)(out + (long)ho * WF + gc) = o;
        }
        hp = hc;
        hc = hn;
    }
}

extern "C" void kernel_launch(void* const* d_in, const int* in_sizes, int n_in,
                              void* d_out, int out_size, void* d_ws, size_t ws_size,
                              hipStream_t stream) {
    const float* in = (const float*)d_in[0];
    float* out      = (float*)d_out;

    // Separable Gaussian weights (double precision on host).
    // 2D normalized kernel == outer([a,b,a],[a,b,a]) with a+b+a == 1.
    const double sig2x2 = 2.0 * 1.3 * 1.3;
    const double e1     = std::exp(-1.0 / sig2x2);
    const double inv1d  = 1.0 / (1.0 + 2.0 * e1);
    const float  wa     = (float)(e1 * inv1d);
    const float  wb     = (float)inv1d;

    const double s  = std::sqrt(1.5);
    const float  c1 = (float)(0.25  * s);
    const float  c3 = (float)(0.625 * s);

    dim3 grid(WF / TW, H / RPT);   // 12 x 256
    anscombe_gauss_kernel<<<grid, 256, 0, stream>>>(in, out, wa, wb, c1, c3);
}